// Round 8
// baseline (429.830 us; speedup 1.0000x reference)
//
#include <hip/hip_runtime.h>

// Problem constants
#define B_   4
#define N_   1024
#define R_   5
#define DIM_ 1024
#define H_   16
#define DH_  64
#define NJ   1056          // padded key count: 1 null + 1024 + 31 pad (33 tiles of 32)
#define CDIM 320           // R_*DH_ effective head width
#define MROWS (B_*N_*R_)   // 20480

typedef unsigned int u32;
typedef unsigned short u16;
typedef __attribute__((ext_vector_type(8))) short bf16x8;
typedef __attribute__((ext_vector_type(4))) float f32x4;
typedef __attribute__((ext_vector_type(16))) float f32x16;

// q-proj scale: DH^-.5 * R^-.5 * log2(e)  (ALPHA net-cancels; log2e folded so softmax uses exp2;
// bias is 0 or -inf so the fold is exact)
constexpr float SCALEA_ = (float)(0.05590169943749474 * 1.4426950408889634);

__device__ __forceinline__ u16 f2bf(float f) {
  u32 u = __builtin_bit_cast(u32, f);
  u32 r = (u + 0x7fffu + ((u >> 16) & 1u)) >> 16;   // RNE
  return (u16)r;
}
__device__ __forceinline__ u32 pack2(float lo, float hi) {
  return (u32)f2bf(lo) | ((u32)f2bf(hi) << 16);
}
__device__ __forceinline__ void gld_lds16(void* lds, const void* g) {
  __builtin_amdgcn_global_load_lds((const __attribute__((address_space(1))) u32*)g,
                                   (__attribute__((address_space(3))) u32*)lds, 16, 0, 0);
}

// ---------------- mask dtype detection (bool may arrive as i8/i32/f32/i64) ----------------
__global__ void mask_detect(const u32* __restrict__ m, int* __restrict__ flag) {
  int t = threadIdx.x;
  int fl = 0;
  for (int i = t; i < 1024; i += 256) {
    u32 wv = m[i];
    if (wv == 0x3f800000u) fl |= 4;
    else if (wv > 1u) fl |= 2;
    if ((i & 1) && wv == 1u) fl |= 1;
  }
  if (fl) atomicOr(flag, fl);
}

__global__ void build_bias(const void* __restrict__ mask, const int* __restrict__ flag,
                           float* __restrict__ biasg) {
  int idx = blockIdx.x * 256 + threadIdx.x;
  if (idx >= B_ * NJ) return;
  int b = idx / NJ, j = idx % NJ;
  int mv;
  if (j == 0) mv = 1;
  else if (j > N_) mv = 0;
  else {
    int fb = flag[0];
    int mode = (fb & 4) ? 2 : ((fb & 2) ? 1 : ((fb & 1) ? 0 : 3));
    int mi = b * N_ + (j - 1);
    if (mode == 0)      mv = ((const int*)mask)[mi] != 0;
    else if (mode == 1) mv = ((const unsigned char*)mask)[mi] != 0;
    else if (mode == 2) mv = ((const float*)mask)[mi] != 0.0f;
    else                mv = ((const int*)mask)[mi * 2] != 0;
  }
  biasg[idx] = mv ? 0.0f : -__builtin_inff();
}

// ---------------- null kv row + pad rows (V is tile-blocked: [b][33][320][32]) ----------------
__global__ void kvfill(const float* __restrict__ nullkv, u16* __restrict__ kg, u16* __restrict__ vTg) {
  int idx = blockIdx.x * 256 + threadIdx.x;
  if (idx >= B_ * 32 * CDIM) return;
  int c  = idx % CDIM;
  int jj = (idx / CDIM) & 31;
  int b  = idx / (CDIM * 32);
  int j  = (jj == 0) ? 0 : (1024 + jj);
  u16 kvv, vvv;
  if (jj == 0) { kvv = f2bf(nullkv[c & 63]); vvv = f2bf(nullkv[64 + (c & 63)]); }
  else         { kvv = 0; vvv = 0; }
  kg [(size_t)(b * NJ + j) * CDIM + c] = kvv;                          // K row-major [B][NJ][320]
  vTg[(((size_t)b * 33 + (j >> 5)) * CDIM + c) * 32 + (j & 31)] = vvv; // V blocked [B][33][320][32]
}

// ---------------- weight transpose + bf16 cast:  WT[n][k] = W[k][n] ----------------
__global__ __launch_bounds__(256) void transpose_cast(const float* __restrict__ W,
                                                      u16* __restrict__ WT, int K, int Nn) {
  __shared__ float tile[32][33];
  int tx = threadIdx.x & 31, ty = threadIdx.x >> 5;
  int n0 = blockIdx.x * 32, k0 = blockIdx.y * 32;
  #pragma unroll
  for (int e = 0; e < 4; ++e)
    tile[ty + e * 8][tx] = W[(size_t)(k0 + ty + e * 8) * Nn + n0 + tx];
  __syncthreads();
  #pragma unroll
  for (int e = 0; e < 4; ++e)
    WT[(size_t)(n0 + ty + e * 8) * K + k0 + tx] = f2bf(tile[tx][ty + e * 8]);
}

// ---------------- input LayerNorm -> xn(bf16), plus raw x cast -> xb(bf16) ----------------
__global__ __launch_bounds__(256) void ln_in(const float* __restrict__ x, const float* __restrict__ gin,
                                             u16* __restrict__ xn, u16* __restrict__ xb) {
  const size_t row = blockIdx.x;
  const int t = threadIdx.x, w = t >> 6, lane = t & 63;
  const float* xr = x + row * 1024;
  f32x4 v = *(const f32x4*)(xr + t * 4);
  float s = v[0] + v[1] + v[2] + v[3];
  #pragma unroll
  for (int o = 1; o < 64; o <<= 1) s += __shfl_xor(s, o);
  __shared__ float red[8];
  if (lane == 0) red[w] = s;
  __syncthreads();
  float mean = (red[0] + red[1] + red[2] + red[3]) * (1.0f / 1024.0f);
  f32x4 d;
  float ss = 0.f;
  #pragma unroll
  for (int e = 0; e < 4; ++e) { d[e] = v[e] - mean; ss += d[e] * d[e]; }
  #pragma unroll
  for (int o = 1; o < 64; o <<= 1) ss += __shfl_xor(ss, o);
  if (lane == 0) red[4 + w] = ss;
  __syncthreads();
  float var = (red[4] + red[5] + red[6] + red[7]) * (1.0f / 1024.0f);
  float rs = rsqrtf(var + 1e-5f);
  f32x4 gv = *(const f32x4*)(gin + t * 4);
  uint2 o1, o2;
  o1.x = pack2(d[0] * rs * gv[0], d[1] * rs * gv[1]);
  o1.y = pack2(d[2] * rs * gv[2], d[3] * rs * gv[3]);
  o2.x = pack2(v[0], v[1]);
  o2.y = pack2(v[2], v[3]);
  *(uint2*)(xn + row * 1024 + t * 4) = o1;
  *(uint2*)(xb + row * 1024 + t * 4) = o2;
}

// ---------------- output LayerNorm: bf16 y in (from gemm<2>), fp32 out ----------------
__global__ __launch_bounds__(256) void ln_out(const u16* __restrict__ yb, const float* __restrict__ gout,
                                              float* __restrict__ out) {
  const size_t row = blockIdx.x;
  const int t = threadIdx.x, w = t >> 6, lane = t & 63;
  uint2 raw = *(const uint2*)(yb + row * 1024 + t * 4);
  f32x4 v;
  v[0] = __builtin_bit_cast(float, (raw.x & 0xffffu) << 16);
  v[1] = __builtin_bit_cast(float, (raw.x & 0xffff0000u));
  v[2] = __builtin_bit_cast(float, (raw.y & 0xffffu) << 16);
  v[3] = __builtin_bit_cast(float, (raw.y & 0xffff0000u));
  float s = v[0] + v[1] + v[2] + v[3];
  #pragma unroll
  for (int o = 1; o < 64; o <<= 1) s += __shfl_xor(s, o);
  __shared__ float red[8];
  if (lane == 0) red[w] = s;
  __syncthreads();
  float mean = (red[0] + red[1] + red[2] + red[3]) * (1.0f / 1024.0f);
  f32x4 d;
  float ss = 0.f;
  #pragma unroll
  for (int e = 0; e < 4; ++e) { d[e] = v[e] - mean; ss += d[e] * d[e]; }
  #pragma unroll
  for (int o = 1; o < 64; o <<= 1) ss += __shfl_xor(ss, o);
  if (lane == 0) red[4 + w] = ss;
  __syncthreads();
  float var = (red[4] + red[5] + red[6] + red[7]) * (1.0f / 1024.0f);
  float rs = rsqrtf(var + 1e-5f);
  f32x4 gv = *(const f32x4*)(gout + t * 4);
  f32x4 o;
  #pragma unroll
  for (int e = 0; e < 4; ++e) o[e] = d[e] * rs * gv[e];
  *(f32x4*)(out + row * 1024 + t * 4) = o;
}

// ---------------- m97-style 128x128 BK=32 bf16 GEMM, B given transposed [N][K] ----------------
// EPI 0: C=bf16 *SCALEA (q-proj). EPI 1: kv scatter. EPI 2: C=bf16 (y for ln_out).
template <int EPI>
__global__ __launch_bounds__(256) void gemm_bt(const u16* __restrict__ A, const u16* __restrict__ BT,
                                               void* __restrict__ C0, void* __restrict__ C1,
                                               const int K, const int Nn) {
  __shared__ __align__(16) u16 As[128 * 32];
  __shared__ __align__(16) u16 Bs[128 * 32];
  const int t = threadIdx.x, w = t >> 6, lane = t & 63;
  const int g = lane >> 4, i16 = lane & 15;
  const int wr = w >> 1, wc = w & 1;
  const size_t m0 = (size_t)blockIdx.y * 128;
  const size_t n0 = (size_t)blockIdx.x * 128;
  const u16* Ab = A + m0 * K;
  const u16* Bb = BT + n0 * K;
  f32x4 acc[4][4];
  #pragma unroll
  for (int mi = 0; mi < 4; ++mi)
    #pragma unroll
    for (int ni = 0; ni < 4; ++ni) acc[mi][ni] = (f32x4){0.f, 0.f, 0.f, 0.f};

  for (int k0 = 0; k0 < K; k0 += 32) {
    __syncthreads();
    #pragma unroll
    for (int s = 0; s < 2; ++s) {
      int c = s * 256 + t;
      gld_lds16(&As[(s * 256 + w * 64) * 8], Ab + (size_t)(c >> 2) * K + k0 + (c & 3) * 8);
      gld_lds16(&Bs[(s * 256 + w * 64) * 8], Bb + (size_t)(c >> 2) * K + k0 + (c & 3) * 8);
    }
    __syncthreads();
    bf16x8 af[4], bfr[4];
    #pragma unroll
    for (int mi = 0; mi < 4; ++mi) af[mi]  = *(const bf16x8*)&As[(wr * 64 + mi * 16 + i16) * 32 + g * 8];
    #pragma unroll
    for (int ni = 0; ni < 4; ++ni) bfr[ni] = *(const bf16x8*)&Bs[(wc * 64 + ni * 16 + i16) * 32 + g * 8];
    #pragma unroll
    for (int mi = 0; mi < 4; ++mi)
      #pragma unroll
      for (int ni = 0; ni < 4; ++ni)
        acc[mi][ni] = __builtin_amdgcn_mfma_f32_16x16x32_bf16(af[mi], bfr[ni], acc[mi][ni], 0, 0, 0);
  }

  #pragma unroll
  for (int mi = 0; mi < 4; ++mi)
    #pragma unroll
    for (int ni = 0; ni < 4; ++ni)
      #pragma unroll
      for (int reg = 0; reg < 4; ++reg) {
        size_t gr = m0 + wr * 64 + mi * 16 + g * 4 + reg;
        int gc = (int)n0 + wc * 64 + ni * 16 + i16;
        float v = acc[mi][ni][reg];
        if (EPI == 0) {
          ((u16*)C0)[gr * 1024 + gc] = f2bf(v * SCALEA_);
        } else if (EPI == 1) {
          int grr = (int)gr;
          int b = grr / (N_ * R_);
          int rem = grr - b * (N_ * R_);
          int n = rem / R_;
          int r = rem - n * R_;
          int j = n + 1;
          u16 val = f2bf(v);
          if (gc < DH_) ((u16*)C0)[(size_t)(b * NJ + j) * CDIM + r * 64 + gc] = val;
          else ((u16*)C1)[(((size_t)b * 33 + (j >> 5)) * CDIM + r * 64 + (gc - DH_)) * 32 + (j & 31)] = val;
        } else {
          ((u16*)C0)[gr * 1024 + gc] = f2bf(v);
        }
      }
}

// ---------------- flash attention v8 ----------------
// v7 + deferred-PV pipeline (T15): the per-tile MFMA cluster is QK(t) interleaved with PV(t-1)
// (independent chains -> issue-bound), softmax(t) produces the P-fragments consumed next tile.
// V is a 3-slot LDS ring so PV(t-1) reads slot (t-1)%3 while staging writes slot (t+1)%3.
// Slot 2 zero-initialized + P-frags start 0 => tile-0 dummy PV contributes exactly 0.
__global__ __launch_bounds__(256, 2) void attn_kernel(const u16* __restrict__ qb, const u16* __restrict__ kg,
                                                      const u16* __restrict__ vTg, const float* __restrict__ biasg,
                                                      u16* __restrict__ attout) {
  const int blk0 = blockIdx.x;
  const int blk = (blk0 & 7) * 128 + (blk0 >> 3);  // XCD-chunked: 128 consecutive per XCD
  const int ch = blk & 1;                           // column half for PV
  const int it = (blk >> 1) & 7;
  const int h  = (blk >> 4) & 15;
  const int b  = blk >> 8;
  const int t = threadIdx.x;
  const int w = t >> 6, lane = t & 63;
  const int l31 = lane & 31, lh = lane >> 5;
  const int i0 = it * 128 + w * 32;

  __shared__ __align__(16) char Kl[2][20480];   // K tile [32 j][320 k] chunk^=f(j)
  __shared__ __align__(16) char Vl[3][10240];   // V half-tile ring [160 c][32 j] chunk^=g(c)

  // ---- staging source offsets (bytes); dest linear, src pre-swizzled (rule #21 both-sides)
  int ksrc[5];
  #pragma unroll
  for (int s = 0; s < 5; ++s) {
    int d = w * 320 + s * 64 + lane;            // K dest 16B-chunk index (1280 chunks)
    int j = d / 40, c16 = d - j * 40;
    int fj = (j & 7) ^ (j >> 3);
    ksrc[s] = j * 640 + ((c16 ^ fj) << 4);
  }
  int vsrc[3];                                  // V: 640 chunks = 2 full stages + half stage (w<2)
  #pragma unroll
  for (int s = 0; s < 3; ++s) {
    int d = s * 256 + t;                        // for s==2 only t<128 participates
    int vc = d >> 2, sl = d & 3;
    int gv = (vc & 3) ^ ((vc >> 3) & 3);
    vsrc[s] = (ch * 160 + vc) * 64 + ((sl ^ gv) << 4);
  }
  const char* ktile = (const char*)(kg + (size_t)b * NJ * CDIM);       // +20480B per j-tile
  const char* vtile = (const char*)(vTg + (size_t)b * 33 * CDIM * 32); // +20480B per j-tile

  // ---- Q fragments: B-operand of 32x32x16; lane: col i = i0+l31, k = kk*16 + lh*8 + e
  bf16x8 qf[20];
  {
    const u16* qrow = qb + ((size_t)(b * N_ + i0 + l31) * R_) * 1024 + h * 64 + lh * 8;
    #pragma unroll
    for (int kk = 0; kk < 20; ++kk) {
      int k16 = kk * 16;
      qf[kk] = *(const bf16x8*)(qrow + (k16 >> 6) * 1024 + (k16 & 63));
    }
  }

  const float* bptr = biasg + b * NJ + lh * 4;

  f32x16 O[5];
  #pragma unroll
  for (int cf = 0; cf < 5; ++cf)
    #pragma unroll
    for (int r = 0; r < 16; ++r) O[cf][r] = 0.f;
  float d_run = 0.f;

  // persistent P fragments (PV operand, produced by softmax(t), consumed at t+1); start 0
  union { u32 u[4]; bf16x8 v; } f1p, f2p;
  #pragma unroll
  for (int e = 0; e < 4; ++e) { f1p.u[e] = 0; f2p.u[e] = 0; }

  // ---- prologue: zero V ring slot 2 (read by the tile-0 dummy PV), stage K(0)->Kl[0], V(0)->Vl[0]
  #pragma unroll
  for (int z = 0; z < 3; ++z) {
    int idx = z * 256 + t;
    if (idx < 640) *(uint4*)&Vl[2][idx * 16] = (uint4){0, 0, 0, 0};
  }
  #pragma unroll
  for (int s = 0; s < 5; ++s)
    gld_lds16(&Kl[0][w * 5120 + s * 1024], ktile + ksrc[s]);
  {
    gld_lds16(&Vl[0][w * 1024],        vtile + vsrc[0]);
    gld_lds16(&Vl[0][4096 + w * 1024], vtile + vsrc[1]);
    if (w < 2) gld_lds16(&Vl[0][8192 + w * 1024], vtile + vsrc[2]);
  }

  const int swzK = ((l31 & 7) ^ (l31 >> 3)) << 4;        // bijective lane->bank (r5: 0 conflicts)
  const int swzV = ((l31 & 3) ^ ((l31 >> 3) & 3)) << 4;

  for (int jt = 0; jt < 33; ++jt) {
    const int cur = jt & 1;
    const int pv  = (jt + 2) % 3;     // ring slot of V(jt-1)

    // one barrier/tile: staged loads issued a full tile ago; lgkm covers prologue ds_writes
    asm volatile("s_waitcnt vmcnt(0) lgkmcnt(0)" ::: "memory");
    __builtin_amdgcn_s_barrier();
    __builtin_amdgcn_sched_barrier(0);

    // issue K(jt+1),V(jt+1); they fly under this tile's compute
    if (jt < 32) {
      const char* kt1 = ktile + (size_t)(jt + 1) * 20480;
      const char* vt1 = vtile + (size_t)(jt + 1) * 20480;
      char* vd = &Vl[(jt + 1) % 3][0];
      #pragma unroll
      for (int s = 0; s < 5; ++s)
        gld_lds16(&Kl[cur ^ 1][w * 5120 + s * 1024], kt1 + ksrc[s]);
      gld_lds16(vd + w * 1024,        vt1 + vsrc[0]);
      gld_lds16(vd + 4096 + w * 1024, vt1 + vsrc[1]);
      if (w < 2) gld_lds16(vd + 8192 + w * 1024, vt1 + vsrc[2]);
    }

    // ---- MFMA cluster: QK(jt) interleaved with PV(jt-1) — 7 independent chains, issue-bound
    const char* Kb  = &Kl[cur][0] + l31 * 640;
    const char* kb0 = Kb + ((0x00 | (lh << 4)) ^ swzK);
    const char* kb1 = Kb + ((0x20 | (lh << 4)) ^ swzK);
    const char* kb2 = Kb + ((0x40 | (lh << 4)) ^ swzK);
    const char* kb3 = Kb + ((0x60 | (lh << 4)) ^ swzK);
    const char* Vb  = &Vl[pv][0] + l31 * 64;
    const char* vb1 = Vb + ((lh << 4) ^ swzV);
    const char* vb2 = Vb + (((lh ^ 2) << 4) ^ swzV);
    f32x16 S0, S1;
    #pragma unroll
    for (int r = 0; r < 16; ++r) { S0[r] = 0.f; S1[r] = 0.f; }
    __builtin_amdgcn_s_setprio(1);
    #pragma unroll
    for (int kk = 0; kk < 20; ++kk) {
      const char* kb = ((kk & 3) == 0) ? kb0 : ((kk & 3) == 1) ? kb1 : ((kk & 3) == 2) ? kb2 : kb3;
      bf16x8 kf = *(const bf16x8*)(kb + (kk >> 2) * 128);
      if (kk & 1) S1 = __builtin_amdgcn_mfma_f32_32x32x16_bf16(kf, qf[kk], S1, 0, 0, 0);
      else        S0 = __builtin_amdgcn_mfma_f32_32x32x16_bf16(kf, qf[kk], S0, 0, 0, 0);
      if (kk < 10) {
        int cf = kk >> 1;
        bf16x8 vv = *(const bf16x8*)(((kk & 1) ? vb2 : vb1) + cf * 2048);
        O[cf] = __builtin_amdgcn_mfma_f32_32x32x16_bf16((kk & 1) ? f2p.v : f1p.v, vv, O[cf], 0, 0, 0);
      }
    }
    __builtin_amdgcn_s_setprio(0);

    // ---- softmax numerator: p = 2^(S + bias2) (log2e pre-folded; clamp = overflow insurance)
    f32x4 bb0 = *(const f32x4*)(bptr + (size_t)jt * 32 + 0);
    f32x4 bb1 = *(const f32x4*)(bptr + (size_t)jt * 32 + 8);
    f32x4 bb2 = *(const f32x4*)(bptr + (size_t)jt * 32 + 16);
    f32x4 bb3 = *(const f32x4*)(bptr + (size_t)jt * 32 + 24);
    float p[16];
    float ts = 0.f;
    #pragma unroll
    for (int r = 0; r < 16; ++r) {
      float bv = (r < 4) ? bb0[r & 3] : (r < 8) ? bb1[r & 3] : (r < 12) ? bb2[r & 3] : bb3[r & 3];
      float L = fminf(S0[r] + S1[r] + bv, 80.0f);
      p[r] = exp2f(L);
      ts += p[r];
    }
    d_run += ts;

    // ---- P -> bf16 A-fragments in-register for NEXT tile's PV: cvt_pk + permlane32_swap
    u32 pk0, pk1, pk2, pk3, pk4, pk5, pk6, pk7;
    asm("v_cvt_pk_bf16_f32 %0, %1, %2" : "=v"(pk0) : "v"(p[0]),  "v"(p[1]));
    asm("v_cvt_pk_bf16_f32 %0, %1, %2" : "=v"(pk1) : "v"(p[2]),  "v"(p[3]));
    asm("v_cvt_pk_bf16_f32 %0, %1, %2" : "=v"(pk2) : "v"(p[4]),  "v"(p[5]));
    asm("v_cvt_pk_bf16_f32 %0, %1, %2" : "=v"(pk3) : "v"(p[6]),  "v"(p[7]));
    asm("v_cvt_pk_bf16_f32 %0, %1, %2" : "=v"(pk4) : "v"(p[8]),  "v"(p[9]));
    asm("v_cvt_pk_bf16_f32 %0, %1, %2" : "=v"(pk5) : "v"(p[10]), "v"(p[11]));
    asm("v_cvt_pk_bf16_f32 %0, %1, %2" : "=v"(pk6) : "v"(p[12]), "v"(p[13]));
    asm("v_cvt_pk_bf16_f32 %0, %1, %2" : "=v"(pk7) : "v"(p[14]), "v"(p[15]));
    asm volatile("v_permlane32_swap_b32 %0, %1" : "+v"(pk0), "+v"(pk2));
    asm volatile("v_permlane32_swap_b32 %0, %1" : "+v"(pk1), "+v"(pk3));
    asm volatile("v_permlane32_swap_b32 %0, %1" : "+v"(pk4), "+v"(pk6));
    asm volatile("v_permlane32_swap_b32 %0, %1" : "+v"(pk5), "+v"(pk7));
    f1p.u[0] = pk0; f1p.u[1] = pk1; f1p.u[2] = pk2; f1p.u[3] = pk3;
    f2p.u[0] = pk4; f2p.u[1] = pk5; f2p.u[2] = pk6; f2p.u[3] = pk7;
  }

  // ---- final PV(32): V(32) lives in ring slot 32%3 == 2; all waves synced at jt=32's barrier
  {
    const char* Vb  = &Vl[2][0] + l31 * 64;
    const char* vb1 = Vb + ((lh << 4) ^ swzV);
    const char* vb2 = Vb + (((lh ^ 2) << 4) ^ swzV);
    __builtin_amdgcn_s_setprio(1);
    #pragma unroll
    for (int cf = 0; cf < 5; ++cf) {
      bf16x8 v0 = *(const bf16x8*)(vb1 + cf * 2048);
      bf16x8 v1 = *(const bf16x8*)(vb2 + cf * 2048);
      O[cf] = __builtin_amdgcn_mfma_f32_32x32x16_bf16(f1p.v, v0, O[cf], 0, 0, 0);
      O[cf] = __builtin_amdgcn_mfma_f32_32x32x16_bf16(f2p.v, v1, O[cf], 0, 0, 0);
    }
    __builtin_amdgcn_s_setprio(0);
  }

  // ---- epilogue: combine halves of d, redistribute 1/d to O's row layout, store half
  d_run += __shfl_xor(d_run, 32);
  float inv = 1.0f / d_run;                 // valid for i = l31
  float invr[16];
  #pragma unroll
  for (int r = 0; r < 16; ++r) invr[r] = __shfl(inv, (r & 3) + 8 * (r >> 2) + 4 * lh);

  #pragma unroll
  for (int r = 0; r < 16; ++r) {
    int gi = i0 + (r & 3) + 8 * (r >> 2) + 4 * lh;
    u16* orow = attout + ((size_t)(b * N_ + gi) * R_) * 1024 + h * 64;
    #pragma unroll
    for (int cf = 0; cf < 5; ++cf) {
      int c = ch * 160 + cf * 32 + l31;
      orow[(c >> 6) * 1024 + (c & 63)] = f2bf(O[cf][r] * invr[r]);
    }
  }
}

extern "C" void kernel_launch(void* const* d_in, const int* in_sizes, int n_in,
                              void* d_out, int out_size, void* d_ws, size_t ws_size,
                              hipStream_t stream) {
  (void)in_sizes; (void)n_in; (void)out_size; (void)ws_size;
  const float* x      = (const float*)d_in[0];
  const void*  mask   = d_in[1];
  const float* g_in   = (const float*)d_in[2];
  const float* Wq     = (const float*)d_in[3];
  const float* Wkv    = (const float*)d_in[4];
  const float* nullkv = (const float*)d_in[5];
  const float* Wout   = (const float*)d_in[6];
  const float* g_out  = (const float*)d_in[7];
  float* out = (float*)d_out;

  char* base = (char*)d_ws;
  size_t off = 0;
  auto carve = [&](size_t bytes) { char* r = base + off; off += (bytes + 255) & ~(size_t)255; return r; };
  int*   flag  = (int*)carve(4);
  float* biasg = (float*)carve((size_t)B_ * NJ * 4);
  u16* WqT   = (u16*)carve((size_t)1024 * 1024 * 2);
  u16* WkvT  = (u16*)carve((size_t)128 * 1024 * 2);
  u16* WoutT = (u16*)carve((size_t)1024 * 1024 * 2);
  u16* xn    = (u16*)carve((size_t)MROWS * 1024 * 2);
  u16* xb    = (u16*)carve((size_t)MROWS * 1024 * 2);
  u16* qb    = (u16*)carve((size_t)MROWS * 1024 * 2);
  u16* kg    = (u16*)carve((size_t)B_ * NJ * CDIM * 2);
  u16* vTg   = (u16*)carve((size_t)B_ * 33 * CDIM * 32 * 2);
  u16* attout = xn;   // xn dead after q-proj; reuse region
  u16* yb     = xb;   // xb dead after kv-proj; reuse for bf16 y (pre-LN)

  hipMemsetAsync(flag, 0, 4, stream);
  mask_detect<<<1, 256, 0, stream>>>((const u32*)mask, flag);
  build_bias<<<(B_ * NJ + 255) / 256, 256, 0, stream>>>(mask, flag, biasg);
  kvfill<<<(B_ * 32 * CDIM + 255) / 256, 256, 0, stream>>>(nullkv, kg, vTg);
  transpose_cast<<<dim3(32, 32), 256, 0, stream>>>(Wq, WqT, 1024, 1024);
  transpose_cast<<<dim3(4, 32), 256, 0, stream>>>(Wkv, WkvT, 1024, 128);
  transpose_cast<<<dim3(32, 32), 256, 0, stream>>>(Wout, WoutT, 1024, 1024);
  ln_in<<<MROWS, 256, 0, stream>>>(x, g_in, xn, xb);
  gemm_bt<0><<<dim3(8, 160), 256, 0, stream>>>(xn, WqT, qb, nullptr, 1024, 1024);
  gemm_bt<1><<<dim3(1, 160), 256, 0, stream>>>(xb, WkvT, kg, vTg, 1024, 128);
  attn_kernel<<<1024, 256, 0, stream>>>(qb, kg, vTg, biasg, attout);
  gemm_bt<2><<<dim3(8, 160), 256, 0, stream>>>(attout, WoutT, yb, nullptr, 1024, 1024);
  ln_out<<<MROWS, 256, 0, stream>>>(yb, g_out, out);
}

// Round 9
// 402.117 us; speedup vs baseline: 1.0689x; 1.0689x over previous
//
#include <hip/hip_runtime.h>

// Problem constants
#define B_   4
#define N_   1024
#define R_   5
#define DIM_ 1024
#define H_   16
#define DH_  64
#define NJ   1056          // padded key count: 1 null + 1024 + 31 pad (33 tiles of 32)
#define CDIM 320           // R_*DH_ effective head width
#define MROWS (B_*N_*R_)   // 20480

typedef unsigned int u32;
typedef unsigned short u16;
typedef __attribute__((ext_vector_type(8))) short bf16x8;
typedef __attribute__((ext_vector_type(4))) float f32x4;
typedef __attribute__((ext_vector_type(16))) float f32x16;

// q-proj scale: DH^-.5 * R^-.5 * log2(e)  (ALPHA net-cancels; log2e folded so softmax uses exp2;
// bias is 0 or -inf so the fold is exact)
constexpr float SCALEA_ = (float)(0.05590169943749474 * 1.4426950408889634);

__device__ __forceinline__ u16 f2bf(float f) {
  u32 u = __builtin_bit_cast(u32, f);
  u32 r = (u + 0x7fffu + ((u >> 16) & 1u)) >> 16;   // RNE
  return (u16)r;
}
__device__ __forceinline__ u32 pack2(float lo, float hi) {
  return (u32)f2bf(lo) | ((u32)f2bf(hi) << 16);
}
__device__ __forceinline__ void gld_lds16(void* lds, const void* g) {
  __builtin_amdgcn_global_load_lds((const __attribute__((address_space(1))) u32*)g,
                                   (__attribute__((address_space(3))) u32*)lds, 16, 0, 0);
}

// ---------------- fused preprocessing: bias (w/ inline mask detect) + kvfill + 3 transposes ----
// grid: [0,17) bias, [17,177) kvfill, [177,1201) Wq^T, [1201,1329) Wkv^T, [1329,2353) Wout^T
__global__ __launch_bounds__(256) void prep(const void* __restrict__ mask, const float* __restrict__ nullkv,
                                            const float* __restrict__ Wq, const float* __restrict__ Wkv,
                                            const float* __restrict__ Wout,
                                            float* __restrict__ biasg, u16* __restrict__ kg,
                                            u16* __restrict__ vTg, u16* __restrict__ WqT,
                                            u16* __restrict__ WkvT, u16* __restrict__ WoutT) {
  const int bid = blockIdx.x, t = threadIdx.x;
  __shared__ int sfl;
  __shared__ float tile[32][33];
  if (bid < 17) {
    // block-local mask dtype detect (bool may arrive as i8/i32/f32/i64); 4KB scan safe under all
    if (t == 0) sfl = 0;
    __syncthreads();
    int fl = 0;
    const u32* mw = (const u32*)mask;
    for (int i = t; i < 1024; i += 256) {
      u32 wv = mw[i];
      if (wv == 0x3f800000u) fl |= 4;       // float 1.0 -> f32 mask
      else if (wv > 1u) fl |= 2;            // packed bytes
      if ((i & 1) && wv == 1u) fl |= 1;     // odd word ==1 -> not i64
    }
    if (fl) atomicOr(&sfl, fl);
    __syncthreads();
    int fb = sfl;
    int idx = bid * 256 + t;
    if (idx < B_ * NJ) {
      int b = idx / NJ, j = idx % NJ;
      int mv;
      if (j == 0) mv = 1;
      else if (j > N_) mv = 0;
      else {
        int mode = (fb & 4) ? 2 : ((fb & 2) ? 1 : ((fb & 1) ? 0 : 3));
        int mi = b * N_ + (j - 1);
        if (mode == 0)      mv = ((const int*)mask)[mi] != 0;
        else if (mode == 1) mv = ((const unsigned char*)mask)[mi] != 0;
        else if (mode == 2) mv = ((const float*)mask)[mi] != 0.0f;
        else                mv = ((const int*)mask)[mi * 2] != 0;
      }
      biasg[idx] = mv ? 0.0f : -__builtin_inff();
    }
  } else if (bid < 177) {
    int idx = (bid - 17) * 256 + t;
    if (idx < B_ * 32 * CDIM) {
      int c  = idx % CDIM;
      int jj = (idx / CDIM) & 31;
      int b  = idx / (CDIM * 32);
      int j  = (jj == 0) ? 0 : (1024 + jj);
      u16 kvv, vvv;
      if (jj == 0) { kvv = f2bf(nullkv[c & 63]); vvv = f2bf(nullkv[64 + (c & 63)]); }
      else         { kvv = 0; vvv = 0; }
      kg [(size_t)(b * NJ + j) * CDIM + c] = kvv;                          // K [B][NJ][320]
      vTg[(((size_t)b * 33 + (j >> 5)) * CDIM + c) * 32 + (j & 31)] = vvv; // V [B][33][320][32]
    }
  } else {
    const float* W; u16* WT; int Nn, id;
    if (bid < 1201)      { W = Wq;   WT = WqT;   Nn = 1024; id = bid - 177; }
    else if (bid < 1329) { W = Wkv;  WT = WkvT;  Nn = 128;  id = bid - 1201; }
    else                 { W = Wout; WT = WoutT; Nn = 1024; id = bid - 1329; }
    const int K = 1024;
    int nb = (Nn == 128) ? 4 : 32;
    int n0 = (id % nb) * 32, k0 = (id / nb) * 32;
    int tx = t & 31, ty = t >> 5;
    #pragma unroll
    for (int e = 0; e < 4; ++e)
      tile[ty + e * 8][tx] = W[(size_t)(k0 + ty + e * 8) * Nn + n0 + tx];
    __syncthreads();
    #pragma unroll
    for (int e = 0; e < 4; ++e)
      WT[(size_t)(n0 + ty + e * 8) * K + k0 + tx] = f2bf(tile[tx][ty + e * 8]);
  }
}

// ---------------- input LayerNorm -> xn(bf16), plus raw x cast -> xb(bf16) ----------------
__global__ __launch_bounds__(256) void ln_in(const float* __restrict__ x, const float* __restrict__ gin,
                                             u16* __restrict__ xn, u16* __restrict__ xb) {
  const size_t row = blockIdx.x;
  const int t = threadIdx.x, w = t >> 6, lane = t & 63;
  const float* xr = x + row * 1024;
  f32x4 v = *(const f32x4*)(xr + t * 4);
  float s = v[0] + v[1] + v[2] + v[3];
  #pragma unroll
  for (int o = 1; o < 64; o <<= 1) s += __shfl_xor(s, o);
  __shared__ float red[8];
  if (lane == 0) red[w] = s;
  __syncthreads();
  float mean = (red[0] + red[1] + red[2] + red[3]) * (1.0f / 1024.0f);
  f32x4 d;
  float ss = 0.f;
  #pragma unroll
  for (int e = 0; e < 4; ++e) { d[e] = v[e] - mean; ss += d[e] * d[e]; }
  #pragma unroll
  for (int o = 1; o < 64; o <<= 1) ss += __shfl_xor(ss, o);
  if (lane == 0) red[4 + w] = ss;
  __syncthreads();
  float var = (red[4] + red[5] + red[6] + red[7]) * (1.0f / 1024.0f);
  float rs = rsqrtf(var + 1e-5f);
  f32x4 gv = *(const f32x4*)(gin + t * 4);
  uint2 o1, o2;
  o1.x = pack2(d[0] * rs * gv[0], d[1] * rs * gv[1]);
  o1.y = pack2(d[2] * rs * gv[2], d[3] * rs * gv[3]);
  o2.x = pack2(v[0], v[1]);
  o2.y = pack2(v[2], v[3]);
  *(uint2*)(xn + row * 1024 + t * 4) = o1;
  *(uint2*)(xb + row * 1024 + t * 4) = o2;
}

// ---------------- output LayerNorm: bf16 y in (from gemm<2>), fp32 out ----------------
__global__ __launch_bounds__(256) void ln_out(const u16* __restrict__ yb, const float* __restrict__ gout,
                                              float* __restrict__ out) {
  const size_t row = blockIdx.x;
  const int t = threadIdx.x, w = t >> 6, lane = t & 63;
  uint2 raw = *(const uint2*)(yb + row * 1024 + t * 4);
  f32x4 v;
  v[0] = __builtin_bit_cast(float, (raw.x & 0xffffu) << 16);
  v[1] = __builtin_bit_cast(float, (raw.x & 0xffff0000u));
  v[2] = __builtin_bit_cast(float, (raw.y & 0xffffu) << 16);
  v[3] = __builtin_bit_cast(float, (raw.y & 0xffff0000u));
  float s = v[0] + v[1] + v[2] + v[3];
  #pragma unroll
  for (int o = 1; o < 64; o <<= 1) s += __shfl_xor(s, o);
  __shared__ float red[8];
  if (lane == 0) red[w] = s;
  __syncthreads();
  float mean = (red[0] + red[1] + red[2] + red[3]) * (1.0f / 1024.0f);
  f32x4 d;
  float ss = 0.f;
  #pragma unroll
  for (int e = 0; e < 4; ++e) { d[e] = v[e] - mean; ss += d[e] * d[e]; }
  #pragma unroll
  for (int o = 1; o < 64; o <<= 1) ss += __shfl_xor(ss, o);
  if (lane == 0) red[4 + w] = ss;
  __syncthreads();
  float var = (red[4] + red[5] + red[6] + red[7]) * (1.0f / 1024.0f);
  float rs = rsqrtf(var + 1e-5f);
  f32x4 gv = *(const f32x4*)(gout + t * 4);
  f32x4 o;
  #pragma unroll
  for (int e = 0; e < 4; ++e) o[e] = d[e] * rs * gv[e];
  *(f32x4*)(out + row * 1024 + t * 4) = o;
}

// ---------------- ring-3 GEMM: 128x128 tile, BK=32, counted vmcnt, swizzled LDS ----------------
// 3-slot LDS ring; stage(t+2) issued after barrier(t); loop-top vmcnt(4) keeps stage(t+1) in
// flight across the barrier (T3+T4). Chunk swizzle cc^=(row&3) both-sides -> conflict-free b128.
// EPI 0: C=bf16 *SCALEA (q-proj). EPI 2: C=bf16 (y for ln_out).
template <int EPI>
__global__ __launch_bounds__(256, 3) void gemm_r3(const u16* __restrict__ A, const u16* __restrict__ BT,
                                                  u16* __restrict__ C0, const int K) {
  __shared__ __align__(16) u16 Al[3][128 * 32];
  __shared__ __align__(16) u16 Bl[3][128 * 32];
  const int t = threadIdx.x, w = t >> 6, lane = t & 63;
  const int g = lane >> 4, i16 = lane & 15;
  const int wr = w >> 1, wc = w & 1;
  const size_t m0 = (size_t)blockIdx.y * 128;
  const size_t n0 = (size_t)blockIdx.x * 128;
  const size_t K2 = (size_t)K * 2;

  // staging source pointers (pre-swizzled chunk col: cc' = cc ^ (row&3)); dest LDS is linear
  const char* asrc[2];
  const char* bsrc[2];
  #pragma unroll
  for (int s = 0; s < 2; ++s) {
    int r = (s * 4 + w) * 16 + (lane >> 2);
    int sw = (((lane & 3) ^ ((lane >> 2) & 3)) << 4);
    asrc[s] = (const char*)(A + m0 * K) + (size_t)r * K2 + sw;
    bsrc[s] = (const char*)(BT + n0 * K) + (size_t)r * K2 + sw;
  }

  f32x4 acc[4][4];
  #pragma unroll
  for (int mi = 0; mi < 4; ++mi)
    #pragma unroll
    for (int ni = 0; ni < 4; ++ni) acc[mi][ni] = (f32x4){0.f, 0.f, 0.f, 0.f};

  auto stage = [&](int kt) {
    const int slot = kt % 3;
    const size_t kb = (size_t)kt * 64;    // 32 u16 = 64 bytes per K-step
    #pragma unroll
    for (int s = 0; s < 2; ++s) {
      gld_lds16(&Al[slot][(s * 4 + w) * 512], asrc[s] + kb);
      gld_lds16(&Bl[slot][(s * 4 + w) * 512], bsrc[s] + kb);
    }
  };

  stage(0);
  stage(1);
  const int NT = K >> 5;
  const int rdsw = ((g ^ (i16 & 3)) << 4);   // read-side swizzle (bytes)

  for (int kt = 0; kt < NT; ++kt) {
    // counted wait: stage(t) landed (own); barrier extends to all waves; stage(t+1) stays in flight
    if (kt < NT - 1) asm volatile("s_waitcnt vmcnt(4)" ::: "memory");
    else             asm volatile("s_waitcnt vmcnt(0)" ::: "memory");
    __builtin_amdgcn_s_barrier();
    __builtin_amdgcn_sched_barrier(0);

    if (kt + 2 < NT) stage(kt + 2);       // slot (kt+2)%3 == (kt-1)%3: free (all waves past t-1)

    const int slot = kt % 3;
    const char* apb = (const char*)&Al[slot][0] + (wr * 64 + i16) * 64 + rdsw;
    const char* bpb = (const char*)&Bl[slot][0] + (wc * 64 + i16) * 64 + rdsw;
    bf16x8 af[4], bfr[4];
    #pragma unroll
    for (int mi = 0; mi < 4; ++mi) af[mi]  = *(const bf16x8*)(apb + mi * 1024);
    #pragma unroll
    for (int ni = 0; ni < 4; ++ni) bfr[ni] = *(const bf16x8*)(bpb + ni * 1024);
    __builtin_amdgcn_s_setprio(1);
    #pragma unroll
    for (int mi = 0; mi < 4; ++mi)
      #pragma unroll
      for (int ni = 0; ni < 4; ++ni)
        acc[mi][ni] = __builtin_amdgcn_mfma_f32_16x16x32_bf16(af[mi], bfr[ni], acc[mi][ni], 0, 0, 0);
    __builtin_amdgcn_s_setprio(0);
  }

  #pragma unroll
  for (int mi = 0; mi < 4; ++mi)
    #pragma unroll
    for (int ni = 0; ni < 4; ++ni)
      #pragma unroll
      for (int reg = 0; reg < 4; ++reg) {
        size_t gr = m0 + wr * 64 + mi * 16 + g * 4 + reg;
        int gc = (int)n0 + wc * 64 + ni * 16 + i16;
        float v = acc[mi][ni][reg];
        C0[gr * 1024 + gc] = f2bf(EPI == 0 ? v * SCALEA_ : v);
      }
}

// ---------------- m97-style 128x128 BK=32 GEMM with kv-scatter epilogue (EPI 1 only) ----------
__global__ __launch_bounds__(256) void gemm_kv(const u16* __restrict__ A, const u16* __restrict__ BT,
                                               u16* __restrict__ C0, u16* __restrict__ C1,
                                               const int K) {
  __shared__ __align__(16) u16 As[128 * 32];
  __shared__ __align__(16) u16 Bs[128 * 32];
  const int t = threadIdx.x, w = t >> 6, lane = t & 63;
  const int g = lane >> 4, i16 = lane & 15;
  const int wr = w >> 1, wc = w & 1;
  const size_t m0 = (size_t)blockIdx.y * 128;
  const size_t n0 = (size_t)blockIdx.x * 128;
  const u16* Ab = A + m0 * K;
  const u16* Bb = BT + n0 * K;
  f32x4 acc[4][4];
  #pragma unroll
  for (int mi = 0; mi < 4; ++mi)
    #pragma unroll
    for (int ni = 0; ni < 4; ++ni) acc[mi][ni] = (f32x4){0.f, 0.f, 0.f, 0.f};

  for (int k0 = 0; k0 < K; k0 += 32) {
    __syncthreads();
    #pragma unroll
    for (int s = 0; s < 2; ++s) {
      int c = s * 256 + t;
      gld_lds16(&As[(s * 256 + w * 64) * 8], Ab + (size_t)(c >> 2) * K + k0 + (c & 3) * 8);
      gld_lds16(&Bs[(s * 256 + w * 64) * 8], Bb + (size_t)(c >> 2) * K + k0 + (c & 3) * 8);
    }
    __syncthreads();
    bf16x8 af[4], bfr[4];
    #pragma unroll
    for (int mi = 0; mi < 4; ++mi) af[mi]  = *(const bf16x8*)&As[(wr * 64 + mi * 16 + i16) * 32 + g * 8];
    #pragma unroll
    for (int ni = 0; ni < 4; ++ni) bfr[ni] = *(const bf16x8*)&Bs[(wc * 64 + ni * 16 + i16) * 32 + g * 8];
    #pragma unroll
    for (int mi = 0; mi < 4; ++mi)
      #pragma unroll
      for (int ni = 0; ni < 4; ++ni)
        acc[mi][ni] = __builtin_amdgcn_mfma_f32_16x16x32_bf16(af[mi], bfr[ni], acc[mi][ni], 0, 0, 0);
  }

  #pragma unroll
  for (int mi = 0; mi < 4; ++mi)
    #pragma unroll
    for (int ni = 0; ni < 4; ++ni)
      #pragma unroll
      for (int reg = 0; reg < 4; ++reg) {
        size_t gr = m0 + wr * 64 + mi * 16 + g * 4 + reg;
        int gc = (int)n0 + wc * 64 + ni * 16 + i16;
        float v = acc[mi][ni][reg];
        int grr = (int)gr;
        int b = grr / (N_ * R_);
        int rem = grr - b * (N_ * R_);
        int n = rem / R_;
        int r = rem - n * R_;
        int j = n + 1;
        u16 val = f2bf(v);
        if (gc < DH_) C0[(size_t)(b * NJ + j) * CDIM + r * 64 + gc] = val;
        else C1[(((size_t)b * 33 + (j >> 5)) * CDIM + r * 64 + (gc - DH_)) * 32 + (j & 31)] = val;
      }
}

// ---------------- flash attention (r7 variant — best measured) ----------------
// One barrier/tile (T3 min-2-phase), K+V double-buffered, exp2 softmax, cvt_pk+permlane P,
// c-split pair covers 320 cols. LDS 61440 -> 2 blocks/CU.
__global__ __launch_bounds__(256, 2) void attn_kernel(const u16* __restrict__ qb, const u16* __restrict__ kg,
                                                      const u16* __restrict__ vTg, const float* __restrict__ biasg,
                                                      u16* __restrict__ attout) {
  const int blk0 = blockIdx.x;
  const int blk = (blk0 & 7) * 128 + (blk0 >> 3);  // XCD-chunked: 128 consecutive per XCD
  const int ch = blk & 1;                           // column half for PV
  const int it = (blk >> 1) & 7;
  const int h  = (blk >> 4) & 15;
  const int b  = blk >> 8;
  const int t = threadIdx.x;
  const int w = t >> 6, lane = t & 63;
  const int l31 = lane & 31, lh = lane >> 5;
  const int i0 = it * 128 + w * 32;

  __shared__ __align__(16) char Kl[2][20480];   // K tile [32 j][320 k] chunk^=f(j)
  __shared__ __align__(16) char Vl[2][10240];   // V half-tile [160 c][32 j] chunk^=g(c)

  int ksrc[5];
  #pragma unroll
  for (int s = 0; s < 5; ++s) {
    int d = w * 320 + s * 64 + lane;
    int j = d / 40, c16 = d - j * 40;
    int fj = (j & 7) ^ (j >> 3);
    ksrc[s] = j * 640 + ((c16 ^ fj) << 4);
  }
  int vsrc[3];
  #pragma unroll
  for (int s = 0; s < 3; ++s) {
    int d = s * 256 + t;
    int vc = d >> 2, sl = d & 3;
    int gv = (vc & 3) ^ ((vc >> 3) & 3);
    vsrc[s] = (ch * 160 + vc) * 64 + ((sl ^ gv) << 4);
  }
  const char* ktile = (const char*)(kg + (size_t)b * NJ * CDIM);
  const char* vtile = (const char*)(vTg + (size_t)b * 33 * CDIM * 32);

  bf16x8 qf[20];
  {
    const u16* qrow = qb + ((size_t)(b * N_ + i0 + l31) * R_) * 1024 + h * 64 + lh * 8;
    #pragma unroll
    for (int kk = 0; kk < 20; ++kk) {
      int k16 = kk * 16;
      qf[kk] = *(const bf16x8*)(qrow + (k16 >> 6) * 1024 + (k16 & 63));
    }
  }

  const float* bptr = biasg + b * NJ + lh * 4;

  f32x16 O[5];
  #pragma unroll
  for (int cf = 0; cf < 5; ++cf)
    #pragma unroll
    for (int r = 0; r < 16; ++r) O[cf][r] = 0.f;
  float d_run = 0.f;

  #pragma unroll
  for (int s = 0; s < 5; ++s)
    gld_lds16(&Kl[0][w * 5120 + s * 1024], ktile + ksrc[s]);
  {
    gld_lds16(&Vl[0][w * 1024],        vtile + vsrc[0]);
    gld_lds16(&Vl[0][4096 + w * 1024], vtile + vsrc[1]);
    if (w < 2) gld_lds16(&Vl[0][8192 + w * 1024], vtile + vsrc[2]);
  }

  const int swzK = ((l31 & 7) ^ (l31 >> 3)) << 4;
  const int swzV = ((l31 & 3) ^ ((l31 >> 3) & 3)) << 4;

  for (int jt = 0; jt < 33; ++jt) {
    const int cur = jt & 1;

    asm volatile("s_waitcnt vmcnt(0)" ::: "memory");
    __builtin_amdgcn_s_barrier();
    __builtin_amdgcn_sched_barrier(0);

    if (jt < 32) {
      const char* kt1 = ktile + (size_t)(jt + 1) * 20480;
      const char* vt1 = vtile + (size_t)(jt + 1) * 20480;
      #pragma unroll
      for (int s = 0; s < 5; ++s)
        gld_lds16(&Kl[cur ^ 1][w * 5120 + s * 1024], kt1 + ksrc[s]);
      gld_lds16(&Vl[cur ^ 1][w * 1024],        vt1 + vsrc[0]);
      gld_lds16(&Vl[cur ^ 1][4096 + w * 1024], vt1 + vsrc[1]);
      if (w < 2) gld_lds16(&Vl[cur ^ 1][8192 + w * 1024], vt1 + vsrc[2]);
    }

    const char* Kb  = &Kl[cur][0] + l31 * 640;
    const char* kb0 = Kb + ((0x00 | (lh << 4)) ^ swzK);
    const char* kb1 = Kb + ((0x20 | (lh << 4)) ^ swzK);
    const char* kb2 = Kb + ((0x40 | (lh << 4)) ^ swzK);
    const char* kb3 = Kb + ((0x60 | (lh << 4)) ^ swzK);
    f32x16 S0, S1;
    #pragma unroll
    for (int r = 0; r < 16; ++r) { S0[r] = 0.f; S1[r] = 0.f; }
    __builtin_amdgcn_s_setprio(1);
    #pragma unroll
    for (int kk = 0; kk < 20; ++kk) {
      const char* kb = ((kk & 3) == 0) ? kb0 : ((kk & 3) == 1) ? kb1 : ((kk & 3) == 2) ? kb2 : kb3;
      bf16x8 kf = *(const bf16x8*)(kb + (kk >> 2) * 128);
      if (kk & 1) S1 = __builtin_amdgcn_mfma_f32_32x32x16_bf16(kf, qf[kk], S1, 0, 0, 0);
      else        S0 = __builtin_amdgcn_mfma_f32_32x32x16_bf16(kf, qf[kk], S0, 0, 0, 0);
    }
    __builtin_amdgcn_s_setprio(0);

    f32x4 bb0 = *(const f32x4*)(bptr + (size_t)jt * 32 + 0);
    f32x4 bb1 = *(const f32x4*)(bptr + (size_t)jt * 32 + 8);
    f32x4 bb2 = *(const f32x4*)(bptr + (size_t)jt * 32 + 16);
    f32x4 bb3 = *(const f32x4*)(bptr + (size_t)jt * 32 + 24);
    float p[16];
    float ts = 0.f;
    #pragma unroll
    for (int r = 0; r < 16; ++r) {
      float bv = (r < 4) ? bb0[r & 3] : (r < 8) ? bb1[r & 3] : (r < 12) ? bb2[r & 3] : bb3[r & 3];
      float L = fminf(S0[r] + S1[r] + bv, 80.0f);
      p[r] = exp2f(L);
      ts += p[r];
    }
    d_run += ts;

    u32 pk0, pk1, pk2, pk3, pk4, pk5, pk6, pk7;
    asm("v_cvt_pk_bf16_f32 %0, %1, %2" : "=v"(pk0) : "v"(p[0]),  "v"(p[1]));
    asm("v_cvt_pk_bf16_f32 %0, %1, %2" : "=v"(pk1) : "v"(p[2]),  "v"(p[3]));
    asm("v_cvt_pk_bf16_f32 %0, %1, %2" : "=v"(pk2) : "v"(p[4]),  "v"(p[5]));
    asm("v_cvt_pk_bf16_f32 %0, %1, %2" : "=v"(pk3) : "v"(p[6]),  "v"(p[7]));
    asm("v_cvt_pk_bf16_f32 %0, %1, %2" : "=v"(pk4) : "v"(p[8]),  "v"(p[9]));
    asm("v_cvt_pk_bf16_f32 %0, %1, %2" : "=v"(pk5) : "v"(p[10]), "v"(p[11]));
    asm("v_cvt_pk_bf16_f32 %0, %1, %2" : "=v"(pk6) : "v"(p[12]), "v"(p[13]));
    asm("v_cvt_pk_bf16_f32 %0, %1, %2" : "=v"(pk7) : "v"(p[14]), "v"(p[15]));
    asm volatile("v_permlane32_swap_b32 %0, %1" : "+v"(pk0), "+v"(pk2));
    asm volatile("v_permlane32_swap_b32 %0, %1" : "+v"(pk1), "+v"(pk3));
    asm volatile("v_permlane32_swap_b32 %0, %1" : "+v"(pk4), "+v"(pk6));
    asm volatile("v_permlane32_swap_b32 %0, %1" : "+v"(pk5), "+v"(pk7));
    union { u32 u[4]; bf16x8 v; } f1, f2;
    f1.u[0] = pk0; f1.u[1] = pk1; f1.u[2] = pk2; f1.u[3] = pk3;
    f2.u[0] = pk4; f2.u[1] = pk5; f2.u[2] = pk6; f2.u[3] = pk7;

    const char* Vb  = &Vl[cur][0] + l31 * 64;
    const char* vb1 = Vb + ((lh << 4) ^ swzV);
    const char* vb2 = Vb + (((lh ^ 2) << 4) ^ swzV);
    __builtin_amdgcn_s_setprio(1);
    #pragma unroll
    for (int cf = 0; cf < 5; ++cf) {
      bf16x8 v0 = *(const bf16x8*)(vb1 + cf * 2048);
      bf16x8 v1 = *(const bf16x8*)(vb2 + cf * 2048);
      O[cf] = __builtin_amdgcn_mfma_f32_32x32x16_bf16(f1.v, v0, O[cf], 0, 0, 0);
      O[cf] = __builtin_amdgcn_mfma_f32_32x32x16_bf16(f2.v, v1, O[cf], 0, 0, 0);
    }
    __builtin_amdgcn_s_setprio(0);
  }

  d_run += __shfl_xor(d_run, 32);
  float inv = 1.0f / d_run;
  float invr[16];
  #pragma unroll
  for (int r = 0; r < 16; ++r) invr[r] = __shfl(inv, (r & 3) + 8 * (r >> 2) + 4 * lh);

  #pragma unroll
  for (int r = 0; r < 16; ++r) {
    int gi = i0 + (r & 3) + 8 * (r >> 2) + 4 * lh;
    u16* orow = attout + ((size_t)(b * N_ + gi) * R_) * 1024 + h * 64;
    #pragma unroll
    for (int cf = 0; cf < 5; ++cf) {
      int c = ch * 160 + cf * 32 + l31;
      orow[(c >> 6) * 1024 + (c & 63)] = f2bf(O[cf][r] * invr[r]);
    }
  }
}

extern "C" void kernel_launch(void* const* d_in, const int* in_sizes, int n_in,
                              void* d_out, int out_size, void* d_ws, size_t ws_size,
                              hipStream_t stream) {
  (void)in_sizes; (void)n_in; (void)out_size; (void)ws_size;
  const float* x      = (const float*)d_in[0];
  const void*  mask   = d_in[1];
  const float* g_in   = (const float*)d_in[2];
  const float* Wq     = (const float*)d_in[3];
  const float* Wkv    = (const float*)d_in[4];
  const float* nullkv = (const float*)d_in[5];
  const float* Wout   = (const float*)d_in[6];
  const float* g_out  = (const float*)d_in[7];
  float* out = (float*)d_out;

  char* base = (char*)d_ws;
  size_t off = 0;
  auto carve = [&](size_t bytes) { char* r = base + off; off += (bytes + 255) & ~(size_t)255; return r; };
  float* biasg = (float*)carve((size_t)B_ * NJ * 4);
  u16* WqT   = (u16*)carve((size_t)1024 * 1024 * 2);
  u16* WkvT  = (u16*)carve((size_t)128 * 1024 * 2);
  u16* WoutT = (u16*)carve((size_t)1024 * 1024 * 2);
  u16* xn    = (u16*)carve((size_t)MROWS * 1024 * 2);
  u16* xb    = (u16*)carve((size_t)MROWS * 1024 * 2);
  u16* qb    = (u16*)carve((size_t)MROWS * 1024 * 2);
  u16* kg    = (u16*)carve((size_t)B_ * NJ * CDIM * 2);
  u16* vTg   = (u16*)carve((size_t)B_ * 33 * CDIM * 32 * 2);
  u16* attout = xn;   // xn dead after q-proj; reuse region
  u16* yb     = xb;   // xb dead after kv-proj; reuse for bf16 y (pre-LN)

  prep<<<2353, 256, 0, stream>>>(mask, nullkv, Wq, Wkv, Wout, biasg, kg, vTg, WqT, WkvT, WoutT);
  ln_in<<<MROWS, 256, 0, stream>>>(x, g_in, xn, xb);
  gemm_r3<0><<<dim3(8, 160), 256, 0, stream>>>(xn, WqT, qb, 1024);
  gemm_kv<<<dim3(1, 160), 256, 0, stream>>>(xb, WkvT, kg, vTg, 1024);
  attn_kernel<<<1024, 256, 0, stream>>>(qb, kg, vTg, biasg, attout);
  gemm_r3<2><<<dim3(8, 160), 256, 0, stream>>>(attout, WoutT, yb, 1024);
  ln_out<<<MROWS, 256, 0, stream>>>(yb, g_out, out);
}

// Round 10
// 364.163 us; speedup vs baseline: 1.1803x; 1.1042x over previous
//
#include <hip/hip_runtime.h>

// Problem constants
#define B_   4
#define N_   1024
#define R_   5
#define DIM_ 1024
#define H_   16
#define DH_  64
#define NJ   1056          // padded key count: 1 null + 1024 + 31 pad (33 tiles of 32)
#define CDIM 320           // R_*DH_ effective head width
#define MROWS (B_*N_*R_)   // 20480

typedef unsigned int u32;
typedef unsigned short u16;
typedef __attribute__((ext_vector_type(8))) short bf16x8;
typedef __attribute__((ext_vector_type(4))) float f32x4;
typedef __attribute__((ext_vector_type(16))) float f32x16;

// q-proj scale: DH^-.5 * R^-.5 * log2(e)  (ALPHA net-cancels; log2e folded so softmax uses exp2;
// bias is 0 or -inf so the fold is exact)
constexpr float SCALEA_ = (float)(0.05590169943749474 * 1.4426950408889634);

__device__ __forceinline__ u16 f2bf(float f) {
  u32 u = __builtin_bit_cast(u32, f);
  u32 r = (u + 0x7fffu + ((u >> 16) & 1u)) >> 16;   // RNE
  return (u16)r;
}
__device__ __forceinline__ u32 pack2(float lo, float hi) {
  return (u32)f2bf(lo) | ((u32)f2bf(hi) << 16);
}
__device__ __forceinline__ void gld_lds16(void* lds, const void* g) {
  __builtin_amdgcn_global_load_lds((const __attribute__((address_space(1))) u32*)g,
                                   (__attribute__((address_space(3))) u32*)lds, 16, 0, 0);
}

// ---------------- fused preprocessing + input LayerNorm ----------------
// grid: [0,17) bias, [17,177) kvfill, [177,1201) Wq^T, [1201,1329) Wkv^T, [1329,2353) Wout^T,
//       [2353, 2353+MROWS) ln_in rows
__global__ __launch_bounds__(256) void prep_ln(const void* __restrict__ mask, const float* __restrict__ nullkv,
                                               const float* __restrict__ Wq, const float* __restrict__ Wkv,
                                               const float* __restrict__ Wout,
                                               const float* __restrict__ x, const float* __restrict__ gin,
                                               float* __restrict__ biasg, u16* __restrict__ kg,
                                               u16* __restrict__ vTg, u16* __restrict__ WqT,
                                               u16* __restrict__ WkvT, u16* __restrict__ WoutT,
                                               u16* __restrict__ xn, u16* __restrict__ xb) {
  const int bid = blockIdx.x, t = threadIdx.x;
  __shared__ int sfl;
  __shared__ float tile[32][33];
  __shared__ float red[8];
  if (bid >= 2353) {
    // ---- input LayerNorm -> xn(bf16), raw x cast -> xb(bf16)
    const size_t row = bid - 2353;
    const int w = t >> 6, lane = t & 63;
    const float* xr = x + row * 1024;
    f32x4 v = *(const f32x4*)(xr + t * 4);
    float s = v[0] + v[1] + v[2] + v[3];
    #pragma unroll
    for (int o = 1; o < 64; o <<= 1) s += __shfl_xor(s, o);
    if (lane == 0) red[w] = s;
    __syncthreads();
    float mean = (red[0] + red[1] + red[2] + red[3]) * (1.0f / 1024.0f);
    f32x4 d;
    float ss = 0.f;
    #pragma unroll
    for (int e = 0; e < 4; ++e) { d[e] = v[e] - mean; ss += d[e] * d[e]; }
    #pragma unroll
    for (int o = 1; o < 64; o <<= 1) ss += __shfl_xor(ss, o);
    if (lane == 0) red[4 + w] = ss;
    __syncthreads();
    float var = (red[4] + red[5] + red[6] + red[7]) * (1.0f / 1024.0f);
    float rs = rsqrtf(var + 1e-5f);
    f32x4 gv = *(const f32x4*)(gin + t * 4);
    uint2 o1, o2;
    o1.x = pack2(d[0] * rs * gv[0], d[1] * rs * gv[1]);
    o1.y = pack2(d[2] * rs * gv[2], d[3] * rs * gv[3]);
    o2.x = pack2(v[0], v[1]);
    o2.y = pack2(v[2], v[3]);
    *(uint2*)(xn + row * 1024 + t * 4) = o1;
    *(uint2*)(xb + row * 1024 + t * 4) = o2;
  } else if (bid < 17) {
    // block-local mask dtype detect (bool may arrive as i8/i32/f32/i64); 4KB scan safe under all
    if (t == 0) sfl = 0;
    __syncthreads();
    int fl = 0;
    const u32* mw = (const u32*)mask;
    for (int i = t; i < 1024; i += 256) {
      u32 wv = mw[i];
      if (wv == 0x3f800000u) fl |= 4;       // float 1.0 -> f32 mask
      else if (wv > 1u) fl |= 2;            // packed bytes
      if ((i & 1) && wv == 1u) fl |= 1;     // odd word ==1 -> not i64
    }
    if (fl) atomicOr(&sfl, fl);
    __syncthreads();
    int fb = sfl;
    int idx = bid * 256 + t;
    if (idx < B_ * NJ) {
      int b = idx / NJ, j = idx % NJ;
      int mv;
      if (j == 0) mv = 1;
      else if (j > N_) mv = 0;
      else {
        int mode = (fb & 4) ? 2 : ((fb & 2) ? 1 : ((fb & 1) ? 0 : 3));
        int mi = b * N_ + (j - 1);
        if (mode == 0)      mv = ((const int*)mask)[mi] != 0;
        else if (mode == 1) mv = ((const unsigned char*)mask)[mi] != 0;
        else if (mode == 2) mv = ((const float*)mask)[mi] != 0.0f;
        else                mv = ((const int*)mask)[mi * 2] != 0;
      }
      biasg[idx] = mv ? 0.0f : -__builtin_inff();
    }
  } else if (bid < 177) {
    int idx = (bid - 17) * 256 + t;
    if (idx < B_ * 32 * CDIM) {
      int c  = idx % CDIM;
      int jj = (idx / CDIM) & 31;
      int b  = idx / (CDIM * 32);
      int j  = (jj == 0) ? 0 : (1024 + jj);
      u16 kvv, vvv;
      if (jj == 0) { kvv = f2bf(nullkv[c & 63]); vvv = f2bf(nullkv[64 + (c & 63)]); }
      else         { kvv = 0; vvv = 0; }
      kg [(size_t)(b * NJ + j) * CDIM + c] = kvv;                          // K [B][NJ][320]
      vTg[(((size_t)b * 33 + (j >> 5)) * CDIM + c) * 32 + (j & 31)] = vvv; // V [B][33][320][32]
    }
  } else {
    const float* W; u16* WT; int Nn, id;
    if (bid < 1201)      { W = Wq;   WT = WqT;   Nn = 1024; id = bid - 177; }
    else if (bid < 1329) { W = Wkv;  WT = WkvT;  Nn = 128;  id = bid - 1201; }
    else                 { W = Wout; WT = WoutT; Nn = 1024; id = bid - 1329; }
    const int K = 1024;
    int nb = (Nn == 128) ? 4 : 32;
    int n0 = (id % nb) * 32, k0 = (id / nb) * 32;
    int tx = t & 31, ty = t >> 5;
    #pragma unroll
    for (int e = 0; e < 4; ++e)
      tile[ty + e * 8][tx] = W[(size_t)(k0 + ty + e * 8) * Nn + n0 + tx];
    __syncthreads();
    #pragma unroll
    for (int e = 0; e < 4; ++e)
      WT[(size_t)(n0 + ty + e * 8) * K + k0 + tx] = f2bf(tile[tx][ty + e * 8]);
  }
}

// ---------------- output LayerNorm: bf16 y in (from gemm<2>), fp32 out ----------------
__global__ __launch_bounds__(256) void ln_out(const u16* __restrict__ yb, const float* __restrict__ gout,
                                              float* __restrict__ out) {
  const size_t row = blockIdx.x;
  const int t = threadIdx.x, w = t >> 6, lane = t & 63;
  uint2 raw = *(const uint2*)(yb + row * 1024 + t * 4);
  f32x4 v;
  v[0] = __builtin_bit_cast(float, (raw.x & 0xffffu) << 16);
  v[1] = __builtin_bit_cast(float, (raw.x & 0xffff0000u));
  v[2] = __builtin_bit_cast(float, (raw.y & 0xffffu) << 16);
  v[3] = __builtin_bit_cast(float, (raw.y & 0xffff0000u));
  float s = v[0] + v[1] + v[2] + v[3];
  #pragma unroll
  for (int o = 1; o < 64; o <<= 1) s += __shfl_xor(s, o);
  __shared__ float red[8];
  if (lane == 0) red[w] = s;
  __syncthreads();
  float mean = (red[0] + red[1] + red[2] + red[3]) * (1.0f / 1024.0f);
  f32x4 d;
  float ss = 0.f;
  #pragma unroll
  for (int e = 0; e < 4; ++e) { d[e] = v[e] - mean; ss += d[e] * d[e]; }
  #pragma unroll
  for (int o = 1; o < 64; o <<= 1) ss += __shfl_xor(ss, o);
  if (lane == 0) red[4 + w] = ss;
  __syncthreads();
  float var = (red[4] + red[5] + red[6] + red[7]) * (1.0f / 1024.0f);
  float rs = rsqrtf(var + 1e-5f);
  f32x4 gv = *(const f32x4*)(gout + t * 4);
  f32x4 o;
  #pragma unroll
  for (int e = 0; e < 4; ++e) o[e] = d[e] * rs * gv[e];
  *(f32x4*)(out + row * 1024 + t * 4) = o;
}

// ---------------- ring-3 GEMM core (128x128 tile, BK=32, counted vmcnt, swizzled LDS) --------
// Shared by proj (q+kv) and out-proj. EPI 0: q (C=bf16 *SCALEA). EPI 1: kv scatter. EPI 2: y bf16.
template <int EPI>
__device__ __forceinline__ void gemm_body(const u16* __restrict__ A, const u16* __restrict__ BT,
                                          u16* __restrict__ C0, u16* __restrict__ C1,
                                          const int K, const size_t m0, const size_t n0,
                                          u16* Al /*3*4096*/, u16* Bl) {
  const int t = threadIdx.x, w = t >> 6, lane = t & 63;
  const int g = lane >> 4, i16 = lane & 15;
  const int wr = w >> 1, wc = w & 1;
  const size_t K2 = (size_t)K * 2;

  // staging source pointers (pre-swizzled chunk col: cc' = cc ^ (row&3)); dest LDS linear
  const char* asrc[2];
  const char* bsrc[2];
  #pragma unroll
  for (int s = 0; s < 2; ++s) {
    int r = (s * 4 + w) * 16 + (lane >> 2);
    int sw = (((lane & 3) ^ ((lane >> 2) & 3)) << 4);
    asrc[s] = (const char*)(A + m0 * K) + (size_t)r * K2 + sw;
    bsrc[s] = (const char*)(BT + n0 * K) + (size_t)r * K2 + sw;
  }

  f32x4 acc[4][4];
  #pragma unroll
  for (int mi = 0; mi < 4; ++mi)
    #pragma unroll
    for (int ni = 0; ni < 4; ++ni) acc[mi][ni] = (f32x4){0.f, 0.f, 0.f, 0.f};

  auto stage = [&](int kt) {
    const int slot = kt % 3;
    const size_t kb = (size_t)kt * 64;    // 32 u16 = 64 bytes per K-step
    #pragma unroll
    for (int s = 0; s < 2; ++s) {
      gld_lds16(&Al[slot * 4096 + (s * 4 + w) * 512], asrc[s] + kb);
      gld_lds16(&Bl[slot * 4096 + (s * 4 + w) * 512], bsrc[s] + kb);
    }
  };

  stage(0);
  stage(1);
  const int NT = K >> 5;
  const int rdsw = ((g ^ (i16 & 3)) << 4);   // read-side swizzle (bytes)

  for (int kt = 0; kt < NT; ++kt) {
    if (kt < NT - 1) asm volatile("s_waitcnt vmcnt(4)" ::: "memory");
    else             asm volatile("s_waitcnt vmcnt(0)" ::: "memory");
    __builtin_amdgcn_s_barrier();
    __builtin_amdgcn_sched_barrier(0);

    if (kt + 2 < NT) stage(kt + 2);       // slot (kt+2)%3 == (kt-1)%3: free (all waves past t-1)

    const int slot = kt % 3;
    const char* apb = (const char*)&Al[slot * 4096] + (wr * 64 + i16) * 64 + rdsw;
    const char* bpb = (const char*)&Bl[slot * 4096] + (wc * 64 + i16) * 64 + rdsw;
    bf16x8 af[4], bfr[4];
    #pragma unroll
    for (int mi = 0; mi < 4; ++mi) af[mi]  = *(const bf16x8*)(apb + mi * 1024);
    #pragma unroll
    for (int ni = 0; ni < 4; ++ni) bfr[ni] = *(const bf16x8*)(bpb + ni * 1024);
    __builtin_amdgcn_s_setprio(1);
    #pragma unroll
    for (int mi = 0; mi < 4; ++mi)
      #pragma unroll
      for (int ni = 0; ni < 4; ++ni)
        acc[mi][ni] = __builtin_amdgcn_mfma_f32_16x16x32_bf16(af[mi], bfr[ni], acc[mi][ni], 0, 0, 0);
    __builtin_amdgcn_s_setprio(0);
  }

  #pragma unroll
  for (int mi = 0; mi < 4; ++mi)
    #pragma unroll
    for (int ni = 0; ni < 4; ++ni)
      #pragma unroll
      for (int reg = 0; reg < 4; ++reg) {
        size_t gr = m0 + wr * 64 + mi * 16 + g * 4 + reg;
        int gc = (int)n0 + wc * 64 + ni * 16 + i16;
        float v = acc[mi][ni][reg];
        if (EPI == 0) {
          C0[gr * 1024 + gc] = f2bf(v * SCALEA_);
        } else if (EPI == 1) {
          int grr = (int)gr;
          int b = grr / (N_ * R_);
          int rem = grr - b * (N_ * R_);
          int n = rem / R_;
          int r = rem - n * R_;
          int j = n + 1;
          u16 val = f2bf(v);
          if (gc < DH_) C0[(size_t)(b * NJ + j) * CDIM + r * 64 + gc] = val;
          else C1[(((size_t)b * 33 + (j >> 5)) * CDIM + r * 64 + (gc - DH_)) * 32 + (j & 31)] = val;
        } else {
          C0[gr * 1024 + gc] = f2bf(v);
        }
      }
}

// combined q-proj + kv-proj: grid 1440 (XCD-chunked); wg%9<8 -> q n-tile, ==8 -> kv
__global__ __launch_bounds__(256, 3) void proj(const u16* __restrict__ xn, const u16* __restrict__ WqT,
                                               u16* __restrict__ qb, const u16* __restrict__ xb,
                                               const u16* __restrict__ WkvT, u16* __restrict__ kg,
                                               u16* __restrict__ vTg) {
  __shared__ __align__(16) u16 Al[3 * 4096];
  __shared__ __align__(16) u16 Bl[3 * 4096];
  const int bid = blockIdx.x;
  const int wg = (bid & 7) * 180 + (bid >> 3);   // 1440%8==0: bijective XCD chunking
  const int xi = wg % 9;
  const size_t m0 = (size_t)(wg / 9) * 128;
  if (xi < 8) gemm_body<0>(xn, WqT, qb, nullptr, 1024, m0, (size_t)xi * 128, Al, Bl);
  else        gemm_body<1>(xb, WkvT, kg, vTg, 1024, m0, 0, Al, Bl);
}

// out-proj: grid 1280 (XCD-chunked)
__global__ __launch_bounds__(256, 3) void outproj(const u16* __restrict__ attout,
                                                  const u16* __restrict__ WoutT, u16* __restrict__ yb) {
  __shared__ __align__(16) u16 Al[3 * 4096];
  __shared__ __align__(16) u16 Bl[3 * 4096];
  const int bid = blockIdx.x;
  const int wg = (bid & 7) * 160 + (bid >> 3);   // 1280%8==0: bijective
  const size_t n0 = (size_t)(wg & 7) * 128;
  const size_t m0 = (size_t)(wg >> 3) * 128;
  gemm_body<2>(attout, WoutT, yb, nullptr, 1024, m0, n0, Al, Bl);
}

// ---------------- flash attention (r7 variant — best measured) ----------------
// One barrier/tile (T3 min-2-phase), K+V double-buffered, exp2 softmax, cvt_pk+permlane P,
// c-split pair covers 320 cols. LDS 61440 -> 2 blocks/CU.
__global__ __launch_bounds__(256, 2) void attn_kernel(const u16* __restrict__ qb, const u16* __restrict__ kg,
                                                      const u16* __restrict__ vTg, const float* __restrict__ biasg,
                                                      u16* __restrict__ attout) {
  const int blk0 = blockIdx.x;
  const int blk = (blk0 & 7) * 128 + (blk0 >> 3);  // XCD-chunked: 128 consecutive per XCD
  const int ch = blk & 1;                           // column half for PV
  const int it = (blk >> 1) & 7;
  const int h  = (blk >> 4) & 15;
  const int b  = blk >> 8;
  const int t = threadIdx.x;
  const int w = t >> 6, lane = t & 63;
  const int l31 = lane & 31, lh = lane >> 5;
  const int i0 = it * 128 + w * 32;

  __shared__ __align__(16) char Kl[2][20480];   // K tile [32 j][320 k] chunk^=f(j)
  __shared__ __align__(16) char Vl[2][10240];   // V half-tile [160 c][32 j] chunk^=g(c)

  int ksrc[5];
  #pragma unroll
  for (int s = 0; s < 5; ++s) {
    int d = w * 320 + s * 64 + lane;
    int j = d / 40, c16 = d - j * 40;
    int fj = (j & 7) ^ (j >> 3);
    ksrc[s] = j * 640 + ((c16 ^ fj) << 4);
  }
  int vsrc[3];
  #pragma unroll
  for (int s = 0; s < 3; ++s) {
    int d = s * 256 + t;
    int vc = d >> 2, sl = d & 3;
    int gv = (vc & 3) ^ ((vc >> 3) & 3);
    vsrc[s] = (ch * 160 + vc) * 64 + ((sl ^ gv) << 4);
  }
  const char* ktile = (const char*)(kg + (size_t)b * NJ * CDIM);
  const char* vtile = (const char*)(vTg + (size_t)b * 33 * CDIM * 32);

  bf16x8 qf[20];
  {
    const u16* qrow = qb + ((size_t)(b * N_ + i0 + l31) * R_) * 1024 + h * 64 + lh * 8;
    #pragma unroll
    for (int kk = 0; kk < 20; ++kk) {
      int k16 = kk * 16;
      qf[kk] = *(const bf16x8*)(qrow + (k16 >> 6) * 1024 + (k16 & 63));
    }
  }

  const float* bptr = biasg + b * NJ + lh * 4;

  f32x16 O[5];
  #pragma unroll
  for (int cf = 0; cf < 5; ++cf)
    #pragma unroll
    for (int r = 0; r < 16; ++r) O[cf][r] = 0.f;
  float d_run = 0.f;

  #pragma unroll
  for (int s = 0; s < 5; ++s)
    gld_lds16(&Kl[0][w * 5120 + s * 1024], ktile + ksrc[s]);
  {
    gld_lds16(&Vl[0][w * 1024],        vtile + vsrc[0]);
    gld_lds16(&Vl[0][4096 + w * 1024], vtile + vsrc[1]);
    if (w < 2) gld_lds16(&Vl[0][8192 + w * 1024], vtile + vsrc[2]);
  }

  const int swzK = ((l31 & 7) ^ (l31 >> 3)) << 4;
  const int swzV = ((l31 & 3) ^ ((l31 >> 3) & 3)) << 4;

  for (int jt = 0; jt < 33; ++jt) {
    const int cur = jt & 1;

    asm volatile("s_waitcnt vmcnt(0)" ::: "memory");
    __builtin_amdgcn_s_barrier();
    __builtin_amdgcn_sched_barrier(0);

    if (jt < 32) {
      const char* kt1 = ktile + (size_t)(jt + 1) * 20480;
      const char* vt1 = vtile + (size_t)(jt + 1) * 20480;
      #pragma unroll
      for (int s = 0; s < 5; ++s)
        gld_lds16(&Kl[cur ^ 1][w * 5120 + s * 1024], kt1 + ksrc[s]);
      gld_lds16(&Vl[cur ^ 1][w * 1024],        vt1 + vsrc[0]);
      gld_lds16(&Vl[cur ^ 1][4096 + w * 1024], vt1 + vsrc[1]);
      if (w < 2) gld_lds16(&Vl[cur ^ 1][8192 + w * 1024], vt1 + vsrc[2]);
    }

    const char* Kb  = &Kl[cur][0] + l31 * 640;
    const char* kb0 = Kb + ((0x00 | (lh << 4)) ^ swzK);
    const char* kb1 = Kb + ((0x20 | (lh << 4)) ^ swzK);
    const char* kb2 = Kb + ((0x40 | (lh << 4)) ^ swzK);
    const char* kb3 = Kb + ((0x60 | (lh << 4)) ^ swzK);
    f32x16 S0, S1;
    #pragma unroll
    for (int r = 0; r < 16; ++r) { S0[r] = 0.f; S1[r] = 0.f; }
    __builtin_amdgcn_s_setprio(1);
    #pragma unroll
    for (int kk = 0; kk < 20; ++kk) {
      const char* kb = ((kk & 3) == 0) ? kb0 : ((kk & 3) == 1) ? kb1 : ((kk & 3) == 2) ? kb2 : kb3;
      bf16x8 kf = *(const bf16x8*)(kb + (kk >> 2) * 128);
      if (kk & 1) S1 = __builtin_amdgcn_mfma_f32_32x32x16_bf16(kf, qf[kk], S1, 0, 0, 0);
      else        S0 = __builtin_amdgcn_mfma_f32_32x32x16_bf16(kf, qf[kk], S0, 0, 0, 0);
    }
    __builtin_amdgcn_s_setprio(0);

    f32x4 bb0 = *(const f32x4*)(bptr + (size_t)jt * 32 + 0);
    f32x4 bb1 = *(const f32x4*)(bptr + (size_t)jt * 32 + 8);
    f32x4 bb2 = *(const f32x4*)(bptr + (size_t)jt * 32 + 16);
    f32x4 bb3 = *(const f32x4*)(bptr + (size_t)jt * 32 + 24);
    float p[16];
    float ts = 0.f;
    #pragma unroll
    for (int r = 0; r < 16; ++r) {
      float bv = (r < 4) ? bb0[r & 3] : (r < 8) ? bb1[r & 3] : (r < 12) ? bb2[r & 3] : bb3[r & 3];
      float L = fminf(S0[r] + S1[r] + bv, 80.0f);
      p[r] = exp2f(L);
      ts += p[r];
    }
    d_run += ts;

    u32 pk0, pk1, pk2, pk3, pk4, pk5, pk6, pk7;
    asm("v_cvt_pk_bf16_f32 %0, %1, %2" : "=v"(pk0) : "v"(p[0]),  "v"(p[1]));
    asm("v_cvt_pk_bf16_f32 %0, %1, %2" : "=v"(pk1) : "v"(p[2]),  "v"(p[3]));
    asm("v_cvt_pk_bf16_f32 %0, %1, %2" : "=v"(pk2) : "v"(p[4]),  "v"(p[5]));
    asm("v_cvt_pk_bf16_f32 %0, %1, %2" : "=v"(pk3) : "v"(p[6]),  "v"(p[7]));
    asm("v_cvt_pk_bf16_f32 %0, %1, %2" : "=v"(pk4) : "v"(p[8]),  "v"(p[9]));
    asm("v_cvt_pk_bf16_f32 %0, %1, %2" : "=v"(pk5) : "v"(p[10]), "v"(p[11]));
    asm("v_cvt_pk_bf16_f32 %0, %1, %2" : "=v"(pk6) : "v"(p[12]), "v"(p[13]));
    asm("v_cvt_pk_bf16_f32 %0, %1, %2" : "=v"(pk7) : "v"(p[14]), "v"(p[15]));
    asm volatile("v_permlane32_swap_b32 %0, %1" : "+v"(pk0), "+v"(pk2));
    asm volatile("v_permlane32_swap_b32 %0, %1" : "+v"(pk1), "+v"(pk3));
    asm volatile("v_permlane32_swap_b32 %0, %1" : "+v"(pk4), "+v"(pk6));
    asm volatile("v_permlane32_swap_b32 %0, %1" : "+v"(pk5), "+v"(pk7));
    union { u32 u[4]; bf16x8 v; } f1, f2;
    f1.u[0] = pk0; f1.u[1] = pk1; f1.u[2] = pk2; f1.u[3] = pk3;
    f2.u[0] = pk4; f2.u[1] = pk5; f2.u[2] = pk6; f2.u[3] = pk7;

    const char* Vb  = &Vl[cur][0] + l31 * 64;
    const char* vb1 = Vb + ((lh << 4) ^ swzV);
    const char* vb2 = Vb + (((lh ^ 2) << 4) ^ swzV);
    __builtin_amdgcn_s_setprio(1);
    #pragma unroll
    for (int cf = 0; cf < 5; ++cf) {
      bf16x8 v0 = *(const bf16x8*)(vb1 + cf * 2048);
      bf16x8 v1 = *(const bf16x8*)(vb2 + cf * 2048);
      O[cf] = __builtin_amdgcn_mfma_f32_32x32x16_bf16(f1.v, v0, O[cf], 0, 0, 0);
      O[cf] = __builtin_amdgcn_mfma_f32_32x32x16_bf16(f2.v, v1, O[cf], 0, 0, 0);
    }
    __builtin_amdgcn_s_setprio(0);
  }

  d_run += __shfl_xor(d_run, 32);
  float inv = 1.0f / d_run;
  float invr[16];
  #pragma unroll
  for (int r = 0; r < 16; ++r) invr[r] = __shfl(inv, (r & 3) + 8 * (r >> 2) + 4 * lh);

  #pragma unroll
  for (int r = 0; r < 16; ++r) {
    int gi = i0 + (r & 3) + 8 * (r >> 2) + 4 * lh;
    u16* orow = attout + ((size_t)(b * N_ + gi) * R_) * 1024 + h * 64;
    #pragma unroll
    for (int cf = 0; cf < 5; ++cf) {
      int c = ch * 160 + cf * 32 + l31;
      orow[(c >> 6) * 1024 + (c & 63)] = f2bf(O[cf][r] * invr[r]);
    }
  }
}

extern "C" void kernel_launch(void* const* d_in, const int* in_sizes, int n_in,
                              void* d_out, int out_size, void* d_ws, size_t ws_size,
                              hipStream_t stream) {
  (void)in_sizes; (void)n_in; (void)out_size; (void)ws_size;
  const float* x      = (const float*)d_in[0];
  const void*  mask   = d_in[1];
  const float* g_in   = (const float*)d_in[2];
  const float* Wq     = (const float*)d_in[3];
  const float* Wkv    = (const float*)d_in[4];
  const float* nullkv = (const float*)d_in[5];
  const float* Wout   = (const float*)d_in[6];
  const float* g_out  = (const float*)d_in[7];
  float* out = (float*)d_out;

  char* base = (char*)d_ws;
  size_t off = 0;
  auto carve = [&](size_t bytes) { char* r = base + off; off += (bytes + 255) & ~(size_t)255; return r; };
  float* biasg = (float*)carve((size_t)B_ * NJ * 4);
  u16* WqT   = (u16*)carve((size_t)1024 * 1024 * 2);
  u16* WkvT  = (u16*)carve((size_t)128 * 1024 * 2);
  u16* WoutT = (u16*)carve((size_t)1024 * 1024 * 2);
  u16* xn    = (u16*)carve((size_t)MROWS * 1024 * 2);
  u16* xb    = (u16*)carve((size_t)MROWS * 1024 * 2);
  u16* qb    = (u16*)carve((size_t)MROWS * 1024 * 2);
  u16* kg    = (u16*)carve((size_t)B_ * NJ * CDIM * 2);
  u16* vTg   = (u16*)carve((size_t)B_ * 33 * CDIM * 32 * 2);
  u16* attout = xn;   // xn dead after q-proj; reuse region
  u16* yb     = xb;   // xb dead after kv-proj; reuse for bf16 y (pre-LN)

  prep_ln<<<2353 + MROWS, 256, 0, stream>>>(mask, nullkv, Wq, Wkv, Wout, x, g_in,
                                            biasg, kg, vTg, WqT, WkvT, WoutT, xn, xb);
  proj<<<1440, 256, 0, stream>>>(xn, WqT, qb, xb, WkvT, kg, vTg);
  attn_kernel<<<1024, 256, 0, stream>>>(qb, kg, vTg, biasg, attout);
  outproj<<<1280, 256, 0, stream>>>(attout, WoutT, yb);
  ln_out<<<MROWS, 256, 0, stream>>>(yb, g_out, out);
}